// Round 10
// baseline (485.780 us; speedup 1.0000x reference)
//
#include <hip/hip_runtime.h>
#include <math.h>

#define BATCH 2
#define TSTEPS 8

typedef __attribute__((ext_vector_type(8))) short s16x8;   // 8 bf16 (4 VGPRs)
typedef __attribute__((ext_vector_type(4))) float f32x4;   // MFMA accum

__device__ __forceinline__ float hsig(float v){ return fminf(fmaxf(0.2f*v+0.5f,0.f),1.f); }

__device__ __forceinline__ ushort f2bf(float f){
    uint u = __builtin_bit_cast(uint, f);
    u = (u + 0x7FFFu + ((u >> 16) & 1u)) >> 16;   // round-to-nearest-even
    return (ushort)u;
}
__device__ __forceinline__ uint pack2bf(float lo, float hi){
    return (uint)f2bf(lo) | ((uint)f2bf(hi) << 16);
}

// async global->LDS DMA, 16 B per lane; LDS dest = wave-uniform base + lane*16
__device__ __forceinline__ void glds16(const ushort* g, ushort* l){
    __builtin_amdgcn_global_load_lds(
        (const __attribute__((address_space(1))) void*)g,
        (__attribute__((address_space(3))) void*)l, 16, 0, 0);
}

// ---------------- fused prep: x cast into PADDED layout + 6 weight transposes ----
template<int K,int N,int Co>
__device__ __forceinline__ void transw1(const float* __restrict__ W, ushort* __restrict__ Wt, int j){
    int n = j / K, k = j - n * K;
    int g = n & 3, co = n >> 2;            // dest row n' = co*4+g
    Wt[j] = f2bf(W[(size_t)k * N + g * Co + co]);
}

#define SZ_X    786432
#define SZ_WX1  884736
#define SZ_WH1  589824
#define SZ_WX2  294912
#define SZ_WH2  147456
#define SZ_WX3  73728
#define SZ_WH3  36864
#define SZ_PREP (SZ_X+SZ_WX1+SZ_WH1+SZ_WX2+SZ_WH2+SZ_WX3+SZ_WH3)

__global__ void prep_kernel(const float* __restrict__ x,
    const float* __restrict__ Wx1, const float* __restrict__ Wh1,
    const float* __restrict__ Wx2, const float* __restrict__ Wh2,
    const float* __restrict__ Wx3, const float* __restrict__ Wh3,
    ushort* __restrict__ xpad,
    ushort* __restrict__ Wxt1, ushort* __restrict__ Wht1,
    ushort* __restrict__ Wxt2, ushort* __restrict__ Wht2,
    ushort* __restrict__ Wxt3, ushort* __restrict__ Wht3)
{
    int i = blockIdx.x * 256 + threadIdx.x;
    if (i < SZ_X){
        int c = i % 192; int r = i / 192;
        int xx = r % 16; r /= 16; int yy = r % 16; int bt = r / 16;
        xpad[((size_t)bt*18*18 + (yy+1)*18 + (xx+1))*192 + c] = f2bf(x[i]);
        return;
    } i -= SZ_X;
    if (i < SZ_WX1){ transw1<1728,512,128>(Wx1, Wxt1, i); return; } i -= SZ_WX1;
    if (i < SZ_WH1){ transw1<1152,512,128>(Wh1, Wht1, i); return; } i -= SZ_WH1;
    if (i < SZ_WX2){ transw1<1152,256, 64>(Wx2, Wxt2, i); return; } i -= SZ_WX2;
    if (i < SZ_WH2){ transw1< 576,256, 64>(Wh2, Wht2, i); return; } i -= SZ_WH2;
    if (i < SZ_WX3){ transw1< 576,128, 32>(Wx3, Wxt3, i); return; } i -= SZ_WX3;
    if (i < SZ_WH3){ transw1< 288,128, 32>(Wh3, Wht3, i); }
}

// ---------------------------------------------------------------------------
// convx: implicit-im2col GEMM, bf16 MFMA. wg = 64x64 (4 waves of 32x32).
// K-loop: per-wave double-buffered LDS staging via global_load_lds (DMA),
// manual s_waitcnt vmcnt(4) pipeline, NO barriers in the loop.
// Input is halo-padded [bt][H+2][W+2][CI] -> no bounds checks at all.
// Epilogue: LDS transpose -> coalesced float4 Zx stores (gate-interleaved).
// ---------------------------------------------------------------------------
template<int CI, int CO, int H, int W>
__global__ __launch_bounds__(256) void convx_dma(
    const ushort* __restrict__ Apad, const ushort* __restrict__ Wt,
    const float* __restrict__ bias, float* __restrict__ Zx)
{
    constexpr int K = 9 * CI, N = 4 * CO;
    constexpr int ITERS = K / 32, CPT = CI / 32;
    constexpr int WP = W + 2, HP = H + 2, HW = H * W;

    __shared__ ushort SA0[4][1024], SA1[4][1024];   // per-wave A dbuf (2 KB each)
    __shared__ ushort SB0[4][1024], SB1[4][1024];   // per-wave B dbuf
    __shared__ float  Zsc[64][68];                  // epilogue transpose

    const int tid = threadIdx.x, lane = tid & 63, wave = tid >> 6;
    const int wm = wave >> 1, wn = wave & 1;
    const int quad = lane >> 4, l16 = lane & 15;
    const int m0 = blockIdx.x * 64 + wm * 32;
    const int n0 = blockIdx.y * 64 + wn * 32;

    // per-lane DMA source bases: lane = quad*16 + l16 handles (pixel l16, ci-chunk quad)
    const ushort* asrc[2]; const ushort* bsrc[2];
    #pragma unroll
    for (int sub = 0; sub < 2; ++sub){
        const int p = m0 + sub * 16 + l16;
        const int bt = p / HW, rem = p - bt * HW;
        const int y = rem / W, x = rem - (rem / W) * W;
        asrc[sub] = Apad + ((size_t)bt * HP * WP + y * WP + x) * CI + quad * 8;
        bsrc[sub] = Wt + (size_t)(n0 + sub * 16 + l16) * K + quad * 8;
    }

    auto issue = [&](int it, int b){
        const int tap = it / CPT, ci0 = (it - tap * CPT) * 32;
        const int kh = tap / 3, kw = tap - (tap / 3) * 3;
        const int aoff = (kh * WP + kw) * CI + ci0;
        ushort* sa = b ? SA1[wave] : SA0[wave];
        ushort* sb = b ? SB1[wave] : SB0[wave];
        #pragma unroll
        for (int sub = 0; sub < 2; ++sub){
            glds16(asrc[sub] + aoff,    sa + sub * 512);
            glds16(bsrc[sub] + it * 32, sb + sub * 512);
        }
    };

    f32x4 acc[2][2] = {};
    issue(0, 0); issue(1, 1);

    #pragma unroll
    for (int it = 0; it < ITERS; ++it){
        if (it + 1 < ITERS) asm volatile("s_waitcnt vmcnt(4)" ::: "memory");
        else                asm volatile("s_waitcnt vmcnt(0)" ::: "memory");
        const ushort* sa = (it & 1) ? SA1[wave] : SA0[wave];
        const ushort* sb = (it & 1) ? SB1[wave] : SB0[wave];
        s16x8 af[2], bf[2];
        #pragma unroll
        for (int mt = 0; mt < 2; ++mt)
            af[mt] = *(const s16x8*)(sa + mt * 512 + quad * 128 + l16 * 8);
        #pragma unroll
        for (int nt = 0; nt < 2; ++nt)
            bf[nt] = *(const s16x8*)(sb + nt * 512 + quad * 128 + l16 * 8);
        #pragma unroll
        for (int mt = 0; mt < 2; ++mt)
            #pragma unroll
            for (int nt = 0; nt < 2; ++nt)
                acc[mt][nt] = __builtin_amdgcn_mfma_f32_16x16x32_bf16(af[mt], bf[nt], acc[mt][nt], 0, 0, 0);
        if (it + 2 < ITERS) issue(it + 2, it & 1);
    }

    // epilogue: bias + LDS transpose + coalesced float4 stores
    #pragma unroll
    for (int mt = 0; mt < 2; ++mt){
        #pragma unroll
        for (int nt = 0; nt < 2; ++nt){
            const int col = n0 + nt * 16 + l16;
            const float bv = bias[(col & 3) * CO + (col >> 2)];
            #pragma unroll
            for (int r = 0; r < 4; ++r)
                Zsc[wm * 32 + mt * 16 + quad * 4 + r][wn * 32 + nt * 16 + l16] = acc[mt][nt][r] + bv;
        }
    }
    __syncthreads();
    const int m0b = blockIdx.x * 64, n0b = blockIdx.y * 64;
    const int sr = tid >> 4, sc = (tid & 15) << 2;
    #pragma unroll
    for (int rr4 = 0; rr4 < 4; ++rr4){
        const int row = rr4 * 16 + sr;
        float4 v = *(float4*)&Zsc[row][sc];
        *(float4*)&Zx[(size_t)(m0b + row) * N + n0b + sc] = v;
    }
}

// ---------------------------------------------------------------------------
// LSTM step: 32x32 tile/wg, K split across 4 waves, each wave runs its own
// DMA-staged double-buffer pipeline (no barriers until the LDS reduce).
// h buffers halo-padded. Epilogue: gates + BN + 2x2 upsample (padded bf16
// activations for blocks 1-2, dense fp32 d_out for block 3).
// ---------------------------------------------------------------------------
template<int CO, int OUT_BF16, int FIRST, int H, int W>
__global__ __launch_bounds__(256) void step_dma(
    const float* __restrict__ Zx, const ushort* __restrict__ Wht,
    const ushort* __restrict__ hprev, ushort* __restrict__ hnew,
    float* __restrict__ cst,
    const float* __restrict__ gamma, const float* __restrict__ beta,
    const float* __restrict__ mmean, const float* __restrict__ mvar,
    void* __restrict__ outp, int t)
{
    constexpr int K = 9 * CO, N4 = 4 * CO;
    constexpr int KITERS = K / 32, CPT = CO / 32;
    constexpr int NJMAX = (KITERS + 3) / 4;
    constexpr int WP = W + 2, HP = H + 2, HW = H * W;

    __shared__ ushort SA0[4][1024], SA1[4][1024];
    __shared__ ushort SB0[4][1024], SB1[4][1024];
    __shared__ float Zs[4][32][36];
    __shared__ float Hs[32][8];

    const int tid = threadIdx.x, lane = tid & 63, wave = tid >> 6;
    const int quad = lane >> 4, l16 = lane & 15;
    const int m0 = blockIdx.x * 32, n0 = blockIdx.y * 32;

    if (!FIRST){
        const ushort* asrc[2]; const ushort* bsrc[2];
        #pragma unroll
        for (int sub = 0; sub < 2; ++sub){
            const int p = m0 + sub * 16 + l16;
            const int b = p / HW, rem = p - b * HW;
            const int y = rem / W, x = rem - (rem / W) * W;
            asrc[sub] = hprev + ((size_t)b * HP * WP + y * WP + x) * CO + quad * 8;
            bsrc[sub] = Wht + (size_t)(n0 + sub * 16 + l16) * K + quad * 8;
        }
        const int nj = (KITERS - wave + 3) >> 2;

        auto issue = [&](int j, int b){
            const int it = wave + 4 * j;
            const int tap = it / CPT, ci0 = (it - tap * CPT) * 32;
            const int kh = tap / 3, kw = tap - (tap / 3) * 3;
            const int aoff = (kh * WP + kw) * CO + ci0;
            ushort* sa = b ? SA1[wave] : SA0[wave];
            ushort* sb = b ? SB1[wave] : SB0[wave];
            #pragma unroll
            for (int sub = 0; sub < 2; ++sub){
                glds16(asrc[sub] + aoff,    sa + sub * 512);
                glds16(bsrc[sub] + it * 32, sb + sub * 512);
            }
        };

        f32x4 acc[2][2] = {};
        if (nj > 0) issue(0, 0);
        if (nj > 1) issue(1, 1);

        #pragma unroll
        for (int j = 0; j < NJMAX; ++j){
            if (j < nj){
                if (j + 1 < nj) asm volatile("s_waitcnt vmcnt(4)" ::: "memory");
                else            asm volatile("s_waitcnt vmcnt(0)" ::: "memory");
                const ushort* sa = (j & 1) ? SA1[wave] : SA0[wave];
                const ushort* sb = (j & 1) ? SB1[wave] : SB0[wave];
                s16x8 af[2], bf[2];
                #pragma unroll
                for (int mt = 0; mt < 2; ++mt)
                    af[mt] = *(const s16x8*)(sa + mt * 512 + quad * 128 + l16 * 8);
                #pragma unroll
                for (int nt = 0; nt < 2; ++nt)
                    bf[nt] = *(const s16x8*)(sb + nt * 512 + quad * 128 + l16 * 8);
                #pragma unroll
                for (int mt = 0; mt < 2; ++mt)
                    #pragma unroll
                    for (int nt = 0; nt < 2; ++nt)
                        acc[mt][nt] = __builtin_amdgcn_mfma_f32_16x16x32_bf16(af[mt], bf[nt], acc[mt][nt], 0, 0, 0);
                if (j + 2 < nj) issue(j + 2, j & 1);
            }
        }

        #pragma unroll
        for (int mt = 0; mt < 2; ++mt)
            #pragma unroll
            for (int nt = 0; nt < 2; ++nt)
                #pragma unroll
                for (int r = 0; r < 4; ++r)
                    Zs[wave][mt * 16 + quad * 4 + r][nt * 16 + l16] = acc[mt][nt][r];
        __syncthreads();
    }

    // gates: 32 pixels x 8 co, one (pixel,co) per thread
    {
        const int pp = tid >> 3, lc = tid & 7;
        const int m = m0 + pp;
        const int b2 = m / HW; const int rr = m - b2 * HW;
        const int y = rr / W, x = rr - (rr / W) * W;
        const int co = (n0 >> 2) + lc;

        const size_t zrow = (size_t)(b2 * TSTEPS + t) * HW + rr;
        const float4 zx = *(const float4*)&Zx[zrow * N4 + n0 + lc * 4];

        float zi = zx.x, zf = zx.y, zg = zx.z, zo = zx.w;
        if (!FIRST){
            const float4 s0 = *(const float4*)&Zs[0][pp][lc * 4];
            const float4 s1 = *(const float4*)&Zs[1][pp][lc * 4];
            const float4 s2 = *(const float4*)&Zs[2][pp][lc * 4];
            const float4 s3 = *(const float4*)&Zs[3][pp][lc * 4];
            zi += s0.x + s1.x + s2.x + s3.x;
            zf += s0.y + s1.y + s2.y + s3.y;
            zg += s0.z + s1.z + s2.z + s3.z;
            zo += s0.w + s1.w + s2.w + s3.w;
        }

        const float iv = hsig(zi), fv = hsig(zf);
        const float gv = tanhf(zg), ov = hsig(zo);
        const float cold = FIRST ? 0.0f : cst[(size_t)m * CO + co];
        const float cn = fv * cold + iv * gv;
        cst[(size_t)m * CO + co] = cn;
        const float h = ov * tanhf(cn);
        hnew[((size_t)b2 * HP * WP + (y + 1) * WP + (x + 1)) * CO + co] = f2bf(h);

        Hs[pp][lc] = (h - mmean[co]) * rsqrtf(mvar[co] + 1e-3f) * gamma[co] + beta[co];
    }
    __syncthreads();

    // coalesced upsampled store
    const int spx = tid >> 3;
    const int m = m0 + spx;
    const int b2 = m / HW; const int rr = m - b2 * HW;
    const int y2 = rr / W, x2 = rr - (rr / W) * W;
    const int co0 = n0 >> 2;

    if (OUT_BF16){
        // padded bf16 activation: [bt][2H+2][2W+2][CO]
        const int q = tid & 7;
        if ((q & 1) == 0){
            const int ypos = q >> 2, xpos = (q >> 1) & 1;
            const float* hsrc = &Hs[spx][0];
            uint4 v;
            v.x = pack2bf(hsrc[0], hsrc[1]); v.y = pack2bf(hsrc[2], hsrc[3]);
            v.z = pack2bf(hsrc[4], hsrc[5]); v.w = pack2bf(hsrc[6], hsrc[7]);
            ushort* o = (ushort*)outp;
            const size_t opix = ((size_t)(b2 * TSTEPS + t) * (2 * H + 2) + 2 * y2 + 1 + ypos) * (2 * W + 2) + 2 * x2 + 1 + xpos;
            *(uint4*)&o[opix * CO + co0] = v;
        }
    } else {
        // dense fp32 final output
        const int q = tid & 7;
        const int ypos = q >> 2, xpos = (q >> 1) & 1, half = q & 1;
        float4 v = *(const float4*)&Hs[spx][half * 4];
        float* o = (float*)outp;
        const size_t opix = ((size_t)(b2 * TSTEPS + t) * 2 * H + 2 * y2 + ypos) * (2 * W) + 2 * x2 + xpos;
        *(float4*)&o[opix * CO + co0 + half * 4] = v;
    }
}

template<int CI, int CO, int H, int W, int OUT_BF16>
static void run_block(const ushort* apad, const ushort* Wxt, const ushort* Wht, const float* bias,
                      const float* g, const float* be, const float* mm, const float* mv,
                      float* Zx, ushort* hApad, ushort* hBpad, float* cbuf, void* out,
                      hipStream_t stream)
{
    const int M = BATCH * TSTEPS * H * W;
    dim3 gx(M / 64, (4 * CO) / 64);
    convx_dma<CI, CO, H, W><<<gx, 256, 0, stream>>>(apad, Wxt, bias, Zx);

    const size_t hbytes = (size_t)BATCH * (H + 2) * (W + 2) * CO * sizeof(ushort);
    hipMemsetAsync(hApad, 0, hbytes, stream);
    hipMemsetAsync(hBpad, 0, hbytes, stream);

    dim3 gs((BATCH * H * W) / 32, (4 * CO) / 32);
    for (int t = 0; t < TSTEPS; ++t){
        const ushort* hp = (t & 1) ? hBpad : hApad;
        ushort* hn = (t & 1) ? hApad : hBpad;
        if (t == 0)
            step_dma<CO, OUT_BF16, 1, H, W><<<gs, 256, 0, stream>>>(Zx, Wht, hp, hn, cbuf, g, be, mm, mv, out, t);
        else
            step_dma<CO, OUT_BF16, 0, H, W><<<gs, 256, 0, stream>>>(Zx, Wht, hp, hn, cbuf, g, be, mm, mv, out, t);
    }
}

extern "C" void kernel_launch(void* const* d_in, const int* in_sizes, int n_in,
                              void* d_out, int out_size, void* d_ws, size_t ws_size,
                              hipStream_t stream) {
    const float* x   = (const float*)d_in[0];
    const float* Wx1 = (const float*)d_in[1];  const float* Wh1 = (const float*)d_in[2];
    const float* b1  = (const float*)d_in[3];  const float* g1  = (const float*)d_in[4];
    const float* be1 = (const float*)d_in[5];  const float* mm1 = (const float*)d_in[6];
    const float* mv1 = (const float*)d_in[7];
    const float* Wx2 = (const float*)d_in[8];  const float* Wh2 = (const float*)d_in[9];
    const float* b2  = (const float*)d_in[10]; const float* g2  = (const float*)d_in[11];
    const float* be2 = (const float*)d_in[12]; const float* mm2 = (const float*)d_in[13];
    const float* mv2 = (const float*)d_in[14];
    const float* Wx3 = (const float*)d_in[15]; const float* Wh3 = (const float*)d_in[16];
    const float* b3  = (const float*)d_in[17]; const float* g3  = (const float*)d_in[18];
    const float* be3 = (const float*)d_in[19]; const float* mm3 = (const float*)d_in[20];
    const float* mv3 = (const float*)d_in[21];

    char* ws = (char*)d_ws;
    size_t off = 0;
    auto alloc = [&](size_t bytes) { char* p = ws + off; off += (bytes + 255) & ~(size_t)255; return p; };

    float*  Zx    = (float*)alloc(8388608ull * 4);       // block3 Zx: 65536 x 128 fp32
    float*  cbuf  = (float*)alloc(262144ull * 4);        // c state (max block3)
    ushort* xpad  = (ushort*)alloc(995328ull * 2);       // 16 x 18x18 x 192
    ushort* x2pad = (ushort*)alloc(2367488ull * 2);      // 16 x 34x34 x 128
    ushort* x3pad = (ushort*)alloc(4460544ull * 2);      // 16 x 66x66 x 64
    ushort* hApad = (ushort*)alloc(278784ull * 2);       // 2 x 66x66 x 32 max
    ushort* hBpad = (ushort*)alloc(278784ull * 2);
    ushort* Wxt1  = (ushort*)alloc(884736ull * 2);
    ushort* Wxt2  = (ushort*)alloc(294912ull * 2);
    ushort* Wxt3  = (ushort*)alloc(73728ull * 2);
    ushort* Wht1  = (ushort*)alloc(589824ull * 2);
    ushort* Wht2  = (ushort*)alloc(147456ull * 2);
    ushort* Wht3  = (ushort*)alloc(36864ull * 2);

    // zero the halo-padded activation buffers (interiors get overwritten)
    hipMemsetAsync(xpad,  0, 995328ull * 2, stream);
    hipMemsetAsync(x2pad, 0, 2367488ull * 2, stream);
    hipMemsetAsync(x3pad, 0, 4460544ull * 2, stream);

    prep_kernel<<<(SZ_PREP + 255) / 256, 256, 0, stream>>>(
        x, Wx1, Wh1, Wx2, Wh2, Wx3, Wh3,
        xpad, Wxt1, Wht1, Wxt2, Wht2, Wxt3, Wht3);

    run_block<192, 128, 16, 16, 1>(xpad,  Wxt1, Wht1, b1, g1, be1, mm1, mv1, Zx, hApad, hBpad, cbuf, x2pad, stream);
    run_block<128,  64, 32, 32, 1>(x2pad, Wxt2, Wht2, b2, g2, be2, mm2, mv2, Zx, hApad, hBpad, cbuf, x3pad, stream);
    run_block< 64,  32, 64, 64, 0>(x3pad, Wxt3, Wht3, b3, g3, be3, mm3, mv3, Zx, hApad, hBpad, cbuf, d_out, stream);
}

// Round 11
// 315.814 us; speedup vs baseline: 1.5382x; 1.5382x over previous
//
#include <hip/hip_runtime.h>
#include <math.h>

#define BATCH 2
#define TSTEPS 8

typedef __attribute__((ext_vector_type(8))) short s16x8;   // 8 bf16
typedef __attribute__((ext_vector_type(4))) float f32x4;   // MFMA accum

__device__ __forceinline__ float hsig(float v){ return fminf(fmaxf(0.2f*v+0.5f,0.f),1.f); }
__device__ __forceinline__ ushort f2bf(float f){
    uint u = __builtin_bit_cast(uint, f);
    u = (u + 0x7FFFu + ((u >> 16) & 1u)) >> 16;
    return (ushort)u;
}
__device__ __forceinline__ uint pack2bf(float lo, float hi){
    return (uint)f2bf(lo) | ((uint)f2bf(hi) << 16);
}

// pack W[k][g*Co+co] fp32 -> fragment-linear bf16:
// dst[((t_n*KCH + c)*64 + quad*16+l)*8 + j] = W[k = c*32+quad*8+j][col n' = t_n*16+l = co*4+g]
template<int KCH, int Co>
__device__ __forceinline__ void packw(const float* __restrict__ W, ushort* __restrict__ dst, int d){
    int j = d & 7, lane = (d >> 3) & 63;
    int q = lane >> 4, l = lane & 15;
    int rest = d >> 9;
    int c = rest % KCH, t_n = rest / KCH;
    int k = c*32 + q*8 + j;
    int np = t_n*16 + l;
    int g = np & 3, co = np >> 2;
    dst[d] = f2bf(W[(size_t)k*(4*Co) + g*Co + co]);
}

#define SZ_X    786432
#define SZ_WX1  884736
#define SZ_WH1  589824
#define SZ_WX2  294912
#define SZ_WH2  147456
#define SZ_WX3  73728
#define SZ_WH3  36864
#define SZ_PREP (SZ_X+SZ_WX1+SZ_WH1+SZ_WX2+SZ_WH2+SZ_WX3+SZ_WH3)

__global__ void prep_kernel(const float* __restrict__ x,
    const float* __restrict__ Wx1, const float* __restrict__ Wh1,
    const float* __restrict__ Wx2, const float* __restrict__ Wh2,
    const float* __restrict__ Wx3, const float* __restrict__ Wh3,
    ushort* __restrict__ xpad,
    ushort* __restrict__ Wxp1, ushort* __restrict__ Whp1,
    ushort* __restrict__ Wxp2, ushort* __restrict__ Whp2,
    ushort* __restrict__ Wxp3, ushort* __restrict__ Whp3)
{
    int i = blockIdx.x * 256 + threadIdx.x;
    if (i < SZ_X){
        int c = i % 192; int r = i / 192;
        int xx = r % 16; r /= 16; int yy = r % 16; int bt = r / 16;
        xpad[((size_t)bt*18*18 + (yy+1)*18 + (xx+1))*192 + c] = f2bf(x[i]);
        return;
    } i -= SZ_X;
    if (i < SZ_WX1){ packw<54,128>(Wx1, Wxp1, i); return; } i -= SZ_WX1;
    if (i < SZ_WH1){ packw<36,128>(Wh1, Whp1, i); return; } i -= SZ_WH1;
    if (i < SZ_WX2){ packw<36, 64>(Wx2, Wxp2, i); return; } i -= SZ_WX2;
    if (i < SZ_WH2){ packw<18, 64>(Wh2, Whp2, i); return; } i -= SZ_WH2;
    if (i < SZ_WX3){ packw<18, 32>(Wx3, Wxp3, i); return; } i -= SZ_WX3;
    if (i < SZ_WH3){ packw< 9, 32>(Wh3, Whp3, i); }
}

// ---------------------------------------------------------------------------
// convx: wg tile 32 px x 64 cols. LDS-resident halo patch (loaded coalesced
// once); B-fragments = single fully-coalesced 16B/lane loads from packed
// weights (fragment-linear). K-loop: 1 global load + 2 ds_read + 2 MFMA,
// no barriers. Epilogue: LDS transpose -> coalesced float4 Zx stores.
// ---------------------------------------------------------------------------
template<int CI, int CO, int H, int W>
__global__ __launch_bounds__(256) void convx_k(
    const ushort* __restrict__ Apad, const ushort* __restrict__ Wpk,
    const float* __restrict__ bias, float* __restrict__ Zx)
{
    constexpr int W_T = (W < 32) ? W : 32;
    constexpr int ROWS = 32 / W_T;
    constexpr int PR = ROWS + 2, PPX = W_T + 2;
    constexpr int PCI = CI + 8;              // PCI % 64 == 8 -> ~conflict-free ds_read_b128
    constexpr int KCH = 9*CI/32, CPT = CI/32;
    constexpr int HW = H*W, HP = H+2, WP = W+2;
    constexpr int N4 = 4*CO;
    constexpr int CH8 = CI/8;
    constexpr int TOT = PR*PPX*CH8;

    __shared__ ushort patch[PR*PPX*PCI];
    __shared__ float Zsc[32][68];

    const int tid = threadIdx.x, lane = tid & 63, wave = tid >> 6;
    const int quad = lane >> 4, l16 = lane & 15;
    const int m0 = blockIdx.x * 32;
    const int bt = m0 / HW, rem = m0 - bt*HW;
    const int y0 = rem / W, x0 = rem - (rem/W)*W;

    // coalesced patch staging (global padded -> LDS with pixel stride PCI)
    const ushort* gsrc = Apad + (size_t)bt*HP*WP*CI;
    for (int c = tid; c < TOT; c += 256){
        int pix = c / CH8, ch = c - pix*CH8;
        int prow = pix / PPX, ppx = pix - prow*PPX;
        *(uint4*)&patch[pix*PCI + ch*8] =
            *(const uint4*)(gsrc + ((size_t)(y0+prow)*WP + (x0+ppx))*CI + ch*8);
    }
    __syncthreads();

    const int t_n = blockIdx.y*4 + wave;     // 16 cols per wave
    const ushort* bptr = Wpk + ((size_t)t_n*KCH*64 + lane)*8;

    int labase[2];
    #pragma unroll
    for (int s = 0; s < 2; ++s){
        int p = s*16 + l16;
        int rp = p / W_T, xp = p - rp*W_T;
        labase[s] = (rp*PPX + xp)*PCI + quad*8;
    }

    f32x4 acc[2] = {};
    #pragma unroll
    for (int it = 0; it < KCH; ++it){
        const int tap = it / CPT, ci0 = (it - tap*CPT)*32;
        const int kh = tap/3, kw = tap - (tap/3)*3;
        const int off = (kh*PPX + kw)*PCI + ci0;
        s16x8 bf = *(const s16x8*)(bptr + (size_t)it*512);
        s16x8 a0 = *(const s16x8*)&patch[labase[0] + off];
        s16x8 a1 = *(const s16x8*)&patch[labase[1] + off];
        acc[0] = __builtin_amdgcn_mfma_f32_16x16x32_bf16(a0, bf, acc[0], 0,0,0);
        acc[1] = __builtin_amdgcn_mfma_f32_16x16x32_bf16(a1, bf, acc[1], 0,0,0);
    }

    const int col = blockIdx.y*64 + wave*16 + l16;   // interleaved col co*4+g
    const float bv = bias[(col & 3)*CO + (col >> 2)];
    #pragma unroll
    for (int s = 0; s < 2; ++s)
        #pragma unroll
        for (int r = 0; r < 4; ++r)
            Zsc[s*16 + quad*4 + r][wave*16 + l16] = acc[s][r] + bv;
    __syncthreads();

    #pragma unroll
    for (int i = 0; i < 2; ++i){
        int c = i*256 + tid;
        int row = c >> 4, cc = (c & 15) << 2;
        *(float4*)&Zx[(size_t)(m0+row)*N4 + blockIdx.y*64 + cc] = *(float4*)&Zsc[row][cc];
    }
}

// ---------------------------------------------------------------------------
// LSTM step: wg tile 32 px x 16 cols (4 co x 4 gates), K split across the 4
// waves (LDS reduce). Same LDS-patch + packed-weight fragment loads.
// Epilogue: gates + BN + 2x2 upsample (padded bf16 for blocks 1-2, fp32 out).
// ---------------------------------------------------------------------------
template<int CO, int H, int W, int OUT_BF16, int FIRST>
__global__ __launch_bounds__(256) void step_k(
    const float* __restrict__ Zx, const ushort* __restrict__ Whpk,
    const ushort* __restrict__ hprev, ushort* __restrict__ hnew,
    float* __restrict__ cst,
    const float* __restrict__ gamma, const float* __restrict__ beta,
    const float* __restrict__ mmean, const float* __restrict__ mvar,
    void* __restrict__ outp, int t)
{
    constexpr int W_T = (W < 32) ? W : 32;
    constexpr int ROWS = 32 / W_T;
    constexpr int PR = ROWS + 2, PPX = W_T + 2;
    constexpr int PCO = CO + 8;
    constexpr int KCH = 9*CO/32, CPT = CO/32;
    constexpr int NJ = (KCH + 3)/4;
    constexpr int HW = H*W, HP = H+2, WP = W+2;
    constexpr int N4 = 4*CO;
    constexpr int CH8 = CO/8;
    constexpr int TOT = PR*PPX*CH8;

    __shared__ ushort patch[PR*PPX*PCO];
    __shared__ float Zs[4][32][20];
    __shared__ float Hs[32][4];

    const int tid = threadIdx.x, lane = tid & 63, wave = tid >> 6;
    const int quad = lane >> 4, l16 = lane & 15;
    const int m0 = blockIdx.x * 32;
    const int b2 = m0 / HW, rem = m0 - b2*HW;
    const int y0 = rem / W, x0 = rem - (rem/W)*W;
    const int t_n = blockIdx.y;
    const int co0 = t_n*4;

    if (!FIRST){
        const ushort* gsrc = hprev + (size_t)b2*HP*WP*CO;
        for (int c = tid; c < TOT; c += 256){
            int pix = c / CH8, ch = c - pix*CH8;
            int prow = pix / PPX, ppx = pix - prow*PPX;
            *(uint4*)&patch[pix*PCO + ch*8] =
                *(const uint4*)(gsrc + ((size_t)(y0+prow)*WP + (x0+ppx))*CO + ch*8);
        }
        __syncthreads();

        const ushort* bptr = Whpk + ((size_t)t_n*KCH*64 + lane)*8;
        int labase[2];
        #pragma unroll
        for (int s = 0; s < 2; ++s){
            int p = s*16 + l16;
            int rp = p / W_T, xp = p - rp*W_T;
            labase[s] = (rp*PPX + xp)*PCO + quad*8;
        }

        f32x4 acc[2] = {};
        const int nj = (KCH - wave + 3) >> 2;
        #pragma unroll
        for (int j = 0; j < NJ; ++j){
            if (j < nj){
                const int it = wave + 4*j;
                const int tap = it / CPT, ci0 = (it - tap*CPT)*32;
                const int kh = tap/3, kw = tap - (tap/3)*3;
                const int off = (kh*PPX + kw)*PCO + ci0;
                s16x8 bf = *(const s16x8*)(bptr + (size_t)it*512);
                s16x8 a0 = *(const s16x8*)&patch[labase[0] + off];
                s16x8 a1 = *(const s16x8*)&patch[labase[1] + off];
                acc[0] = __builtin_amdgcn_mfma_f32_16x16x32_bf16(a0, bf, acc[0], 0,0,0);
                acc[1] = __builtin_amdgcn_mfma_f32_16x16x32_bf16(a1, bf, acc[1], 0,0,0);
            }
        }
        #pragma unroll
        for (int s = 0; s < 2; ++s)
            #pragma unroll
            for (int r = 0; r < 4; ++r)
                Zs[wave][s*16 + quad*4 + r][l16] = acc[s][r];
        __syncthreads();
    }

    // gates: 32 px x 4 co (tid < 128)
    if (tid < 128){
        const int px = tid >> 2, coin = tid & 3;
        const int m = m0 + px;
        const int rr = m - b2*HW;
        const int co = co0 + coin;
        const size_t zrow = (size_t)(b2*TSTEPS + t)*HW + rr;
        const float4 zx = *(const float4*)&Zx[zrow*N4 + t_n*16 + coin*4];
        float zi = zx.x, zf = zx.y, zg = zx.z, zo = zx.w;
        if (!FIRST){
            #pragma unroll
            for (int w = 0; w < 4; ++w){
                const float4 s = *(const float4*)&Zs[w][px][coin*4];
                zi += s.x; zf += s.y; zg += s.z; zo += s.w;
            }
        }
        const float iv = hsig(zi), fv = hsig(zf);
        const float gv = tanhf(zg), ov = hsig(zo);
        const float cold = FIRST ? 0.f : cst[(size_t)m*CO + co];
        const float cn = fv*cold + iv*gv;
        cst[(size_t)m*CO + co] = cn;
        const float h = ov * tanhf(cn);
        const int y = rr / W, x = rr - (rr/W)*W;
        hnew[((size_t)b2*HP*WP + (y+1)*WP + (x+1))*CO + co] = f2bf(h);
        Hs[px][coin] = (h - mmean[co])*rsqrtf(mvar[co]+1e-3f)*gamma[co] + beta[co];
    }
    __syncthreads();

    // 2x2 upsampled store: 32 px * 4 positions (tid < 128)
    if (tid < 128){
        const int px = tid >> 2, q = tid & 3;
        const int ypos = q >> 1, xpos = q & 1;
        const int m = m0 + px;
        const int rr = m - b2*HW;
        const int y = rr / W, x = rr - (rr/W)*W;
        if (OUT_BF16){
            uint2 v; v.x = pack2bf(Hs[px][0], Hs[px][1]); v.y = pack2bf(Hs[px][2], Hs[px][3]);
            ushort* o = (ushort*)outp;
            const size_t opix = ((size_t)(b2*TSTEPS + t)*(2*H+2) + 2*y+1+ypos)*(size_t)(2*W+2) + 2*x+1+xpos;
            *(uint2*)&o[opix*CO + co0] = v;
        } else {
            float4 v = *(const float4*)&Hs[px][0];
            float* o = (float*)outp;
            const size_t opix = ((size_t)(b2*TSTEPS + t)*(2*H) + 2*y+ypos)*(size_t)(2*W) + 2*x+xpos;
            *(float4*)&o[opix*CO + co0] = v;
        }
    }
}

template<int CI, int CO, int H, int W, int OUT_BF16>
static void run_block(const ushort* apad, const ushort* Wxp, const ushort* Whp, const float* bias,
                      const float* g, const float* be, const float* mm, const float* mv,
                      float* Zx, ushort* hApad, ushort* hBpad, float* cbuf, void* out,
                      hipStream_t stream)
{
    const int M = BATCH * TSTEPS * H * W;
    dim3 gx(M / 32, (4*CO) / 64);
    convx_k<CI, CO, H, W><<<gx, 256, 0, stream>>>(apad, Wxp, bias, Zx);

    const size_t hbytes = (size_t)BATCH * (H+2) * (W+2) * CO * sizeof(ushort);
    hipMemsetAsync(hApad, 0, hbytes, stream);
    hipMemsetAsync(hBpad, 0, hbytes, stream);

    dim3 gs((BATCH * H * W) / 32, (4*CO) / 16);
    for (int t = 0; t < TSTEPS; ++t){
        const ushort* hp = (t & 1) ? hBpad : hApad;
        ushort* hn = (t & 1) ? hApad : hBpad;
        if (t == 0)
            step_k<CO, H, W, OUT_BF16, 1><<<gs, 256, 0, stream>>>(Zx, Whp, hp, hn, cbuf, g, be, mm, mv, out, t);
        else
            step_k<CO, H, W, OUT_BF16, 0><<<gs, 256, 0, stream>>>(Zx, Whp, hp, hn, cbuf, g, be, mm, mv, out, t);
    }
}

extern "C" void kernel_launch(void* const* d_in, const int* in_sizes, int n_in,
                              void* d_out, int out_size, void* d_ws, size_t ws_size,
                              hipStream_t stream) {
    const float* x   = (const float*)d_in[0];
    const float* Wx1 = (const float*)d_in[1];  const float* Wh1 = (const float*)d_in[2];
    const float* b1  = (const float*)d_in[3];  const float* g1  = (const float*)d_in[4];
    const float* be1 = (const float*)d_in[5];  const float* mm1 = (const float*)d_in[6];
    const float* mv1 = (const float*)d_in[7];
    const float* Wx2 = (const float*)d_in[8];  const float* Wh2 = (const float*)d_in[9];
    const float* b2  = (const float*)d_in[10]; const float* g2  = (const float*)d_in[11];
    const float* be2 = (const float*)d_in[12]; const float* mm2 = (const float*)d_in[13];
    const float* mv2 = (const float*)d_in[14];
    const float* Wx3 = (const float*)d_in[15]; const float* Wh3 = (const float*)d_in[16];
    const float* b3  = (const float*)d_in[17]; const float* g3  = (const float*)d_in[18];
    const float* be3 = (const float*)d_in[19]; const float* mm3 = (const float*)d_in[20];
    const float* mv3 = (const float*)d_in[21];

    char* ws = (char*)d_ws;
    size_t off = 0;
    auto alloc = [&](size_t bytes) { char* p = ws + off; off += (bytes + 255) & ~(size_t)255; return p; };

    float*  Zx    = (float*)alloc(8388608ull * 4);       // block3 Zx: 65536 x 128 fp32
    float*  cbuf  = (float*)alloc(262144ull * 4);        // c state (max block3)
    ushort* xpad  = (ushort*)alloc(995328ull * 2);       // 16 x 18x18 x 192
    ushort* x2pad = (ushort*)alloc(2367488ull * 2);      // 16 x 34x34 x 128
    ushort* x3pad = (ushort*)alloc(4460544ull * 2);      // 16 x 66x66 x 64
    ushort* hApad = (ushort*)alloc(278784ull * 2);       // 2 x 66x66 x 32 max
    ushort* hBpad = (ushort*)alloc(278784ull * 2);
    ushort* Wxp1  = (ushort*)alloc(884736ull * 2);
    ushort* Wxp2  = (ushort*)alloc(294912ull * 2);
    ushort* Wxp3  = (ushort*)alloc(73728ull * 2);
    ushort* Whp1  = (ushort*)alloc(589824ull * 2);
    ushort* Whp2  = (ushort*)alloc(147456ull * 2);
    ushort* Whp3  = (ushort*)alloc(36864ull * 2);

    hipMemsetAsync(xpad,  0, 995328ull * 2, stream);
    hipMemsetAsync(x2pad, 0, 2367488ull * 2, stream);
    hipMemsetAsync(x3pad, 0, 4460544ull * 2, stream);

    prep_kernel<<<(SZ_PREP + 255) / 256, 256, 0, stream>>>(
        x, Wx1, Wh1, Wx2, Wh2, Wx3, Wh3,
        xpad, Wxp1, Whp1, Wxp2, Whp2, Wxp3, Whp3);

    run_block<192, 128, 16, 16, 1>(xpad,  Wxp1, Whp1, b1, g1, be1, mm1, mv1, Zx, hApad, hBpad, cbuf, x2pad, stream);
    run_block<128,  64, 32, 32, 1>(x2pad, Wxp2, Whp2, b2, g2, be2, mm2, mv2, Zx, hApad, hBpad, cbuf, x3pad, stream);
    run_block< 64,  32, 64, 64, 0>(x3pad, Wxp3, Whp3, b3, g3, be3, mm3, mv3, Zx, hApad, hBpad, cbuf, d_out, stream);
}

// Round 12
// 310.840 us; speedup vs baseline: 1.5628x; 1.0160x over previous
//
#include <hip/hip_runtime.h>
#include <math.h>

#define BATCH 2
#define TSTEPS 8

typedef __attribute__((ext_vector_type(8))) short s16x8;   // 8 bf16
typedef __attribute__((ext_vector_type(4))) float f32x4;   // MFMA accum

__device__ __forceinline__ float hsig(float v){ return fminf(fmaxf(0.2f*v+0.5f,0.f),1.f); }
__device__ __forceinline__ ushort f2bf(float f){
    uint u = __builtin_bit_cast(uint, f);
    u = (u + 0x7FFFu + ((u >> 16) & 1u)) >> 16;
    return (ushort)u;
}
__device__ __forceinline__ uint pack2bf(float lo, float hi){
    return (uint)f2bf(lo) | ((uint)f2bf(hi) << 16);
}

// pack W[k][g*Co+co] fp32 -> fragment-linear bf16:
// dst[((t_n*KCH + c)*64 + quad*16+l)*8 + j] = W[k=c*32+quad*8+j][n'=t_n*16+l, n'=co*4+g]
template<int KCH, int Co>
__device__ __forceinline__ void packw(const float* __restrict__ W, ushort* __restrict__ dst, int d){
    int j = d & 7, lane = (d >> 3) & 63;
    int q = lane >> 4, l = lane & 15;
    int rest = d >> 9;
    int c = rest % KCH, t_n = rest / KCH;
    int k = c*32 + q*8 + j;
    int np = t_n*16 + l;
    int g = np & 3, co = np >> 2;
    dst[d] = f2bf(W[(size_t)k*(4*Co) + g*Co + co]);
}

#define SZ_X    786432
#define SZ_WX1  884736
#define SZ_WH1  589824
#define SZ_WX2  294912
#define SZ_WH2  147456
#define SZ_WX3  73728
#define SZ_WH3  36864
#define SZ_PREP (SZ_X+SZ_WX1+SZ_WH1+SZ_WX2+SZ_WH2+SZ_WX3+SZ_WH3)

__global__ void prep_kernel(const float* __restrict__ x,
    const float* __restrict__ Wx1, const float* __restrict__ Wh1,
    const float* __restrict__ Wx2, const float* __restrict__ Wh2,
    const float* __restrict__ Wx3, const float* __restrict__ Wh3,
    ushort* __restrict__ xpad,
    ushort* __restrict__ Wxp1, ushort* __restrict__ Whp1,
    ushort* __restrict__ Wxp2, ushort* __restrict__ Whp2,
    ushort* __restrict__ Wxp3, ushort* __restrict__ Whp3)
{
    int i = blockIdx.x * 256 + threadIdx.x;
    if (i < SZ_X){
        int c = i % 192; int r = i / 192;
        int xx = r % 16; r /= 16; int yy = r % 16; int bt = r / 16;
        xpad[((size_t)bt*18*18 + (yy+1)*18 + (xx+1))*192 + c] = f2bf(x[i]);
        return;
    } i -= SZ_X;
    if (i < SZ_WX1){ packw<54,128>(Wx1, Wxp1, i); return; } i -= SZ_WX1;
    if (i < SZ_WH1){ packw<36,128>(Wh1, Whp1, i); return; } i -= SZ_WH1;
    if (i < SZ_WX2){ packw<36, 64>(Wx2, Wxp2, i); return; } i -= SZ_WX2;
    if (i < SZ_WH2){ packw<18, 64>(Wh2, Whp2, i); return; } i -= SZ_WH2;
    if (i < SZ_WX3){ packw<18, 32>(Wx3, Wxp3, i); return; } i -= SZ_WX3;
    if (i < SZ_WH3){ packw< 9, 32>(Wh3, Whp3, i); }
}

// ---------------------------------------------------------------------------
// convx: wg tile 32 px x 128 cols; each wave = 32 px x 32 cols (2 B-frags).
// LDS halo patch staged once; per k-iter: 2 coalesced B loads + 2 ds_read_b128
// + 4 MFMA, no barriers. Epilogue: LDS transpose -> coalesced float4 stores.
// ---------------------------------------------------------------------------
template<int CI, int CO, int H, int W>
__global__ __launch_bounds__(256) void convx_k(
    const ushort* __restrict__ Apad, const ushort* __restrict__ Wpk,
    const float* __restrict__ bias, float* __restrict__ Zx)
{
    constexpr int W_T = (W < 32) ? W : 32;
    constexpr int ROWS = 32 / W_T;
    constexpr int PR = ROWS + 2, PPX = W_T + 2;
    constexpr int PCI = CI + 8;
    constexpr int KCH = 9*CI/32, CPT = CI/32;
    constexpr int HW = H*W, HP = H+2, WP = W+2;
    constexpr int N4 = 4*CO;
    constexpr int CH8 = CI/8;
    constexpr int TOT = PR*PPX*CH8;

    __shared__ ushort patch[PR*PPX*PCI];
    __shared__ float Zsc[32][132];

    const int tid = threadIdx.x, lane = tid & 63, wave = tid >> 6;
    const int quad = lane >> 4, l16 = lane & 15;
    const int m0 = blockIdx.x * 32;
    const int bt = m0 / HW, rem = m0 - bt*HW;
    const int y0 = rem / W, x0 = rem - (rem/W)*W;

    const ushort* gsrc = Apad + (size_t)bt*HP*WP*CI;
    for (int c = tid; c < TOT; c += 256){
        int pix = c / CH8, ch = c - pix*CH8;
        int prow = pix / PPX, ppx = pix - prow*PPX;
        *(uint4*)&patch[pix*PCI + ch*8] =
            *(const uint4*)(gsrc + ((size_t)(y0+prow)*WP + (x0+ppx))*CI + ch*8);
    }
    __syncthreads();

    const int tn0 = blockIdx.y*8 + wave*2;   // wave covers 2 16-col tiles
    const ushort* bptr0 = Wpk + ((size_t)tn0*KCH*64 + lane)*8;
    const ushort* bptr1 = Wpk + ((size_t)(tn0+1)*KCH*64 + lane)*8;

    int labase[2];
    #pragma unroll
    for (int s = 0; s < 2; ++s){
        int p = s*16 + l16;
        int rp = p / W_T, xp = p - rp*W_T;
        labase[s] = (rp*PPX + xp)*PCI + quad*8;
    }

    f32x4 acc[2][2] = {};
    #pragma unroll
    for (int it = 0; it < KCH; ++it){
        const int tap = it / CPT, ci0 = (it - tap*CPT)*32;
        const int kh = tap/3, kw = tap - (tap/3)*3;
        const int off = (kh*PPX + kw)*PCI + ci0;
        s16x8 b0 = *(const s16x8*)(bptr0 + (size_t)it*512);
        s16x8 b1 = *(const s16x8*)(bptr1 + (size_t)it*512);
        s16x8 a0 = *(const s16x8*)&patch[labase[0] + off];
        s16x8 a1 = *(const s16x8*)&patch[labase[1] + off];
        acc[0][0] = __builtin_amdgcn_mfma_f32_16x16x32_bf16(a0, b0, acc[0][0], 0,0,0);
        acc[0][1] = __builtin_amdgcn_mfma_f32_16x16x32_bf16(a0, b1, acc[0][1], 0,0,0);
        acc[1][0] = __builtin_amdgcn_mfma_f32_16x16x32_bf16(a1, b0, acc[1][0], 0,0,0);
        acc[1][1] = __builtin_amdgcn_mfma_f32_16x16x32_bf16(a1, b1, acc[1][1], 0,0,0);
    }

    #pragma unroll
    for (int s = 0; s < 2; ++s){
        #pragma unroll
        for (int nt = 0; nt < 2; ++nt){
            const int col = blockIdx.y*128 + wave*32 + nt*16 + l16;
            const float bv = bias[(col & 3)*CO + (col >> 2)];
            #pragma unroll
            for (int r = 0; r < 4; ++r)
                Zsc[s*16 + quad*4 + r][wave*32 + nt*16 + l16] = acc[s][nt][r] + bv;
        }
    }
    __syncthreads();

    #pragma unroll
    for (int i = 0; i < 4; ++i){
        int c = i*256 + tid;
        int row = c >> 5, cc = (c & 31) << 2;
        *(float4*)&Zx[(size_t)(m0+row)*N4 + blockIdx.y*128 + cc] = *(float4*)&Zsc[row][cc];
    }
}

// ---------------------------------------------------------------------------
// LSTM step: wg tile 32 px x 32 cols (8 co x 4 gates), K split across 4 waves
// (each wave: 2 B-frags, 4 MFMA/iter), LDS reduce, fused epilogue with
// packed coalesced upsample stores.
// ---------------------------------------------------------------------------
template<int CO, int H, int W, int OUT_BF16, int FIRST>
__global__ __launch_bounds__(256) void step_k(
    const float* __restrict__ Zx, const ushort* __restrict__ Whpk,
    const ushort* __restrict__ hprev, ushort* __restrict__ hnew,
    float* __restrict__ cst,
    const float* __restrict__ gamma, const float* __restrict__ beta,
    const float* __restrict__ mmean, const float* __restrict__ mvar,
    void* __restrict__ outp, int t)
{
    constexpr int W_T = (W < 32) ? W : 32;
    constexpr int ROWS = 32 / W_T;
    constexpr int PR = ROWS + 2, PPX = W_T + 2;
    constexpr int PCO = CO + 8;
    constexpr int KCH = 9*CO/32, CPT = CO/32;
    constexpr int NJ = (KCH + 3)/4;
    constexpr int HW = H*W, HP = H+2, WP = W+2;
    constexpr int N4 = 4*CO;
    constexpr int CH8 = CO/8;
    constexpr int TOT = PR*PPX*CH8;

    __shared__ ushort patch[PR*PPX*PCO];
    __shared__ float Zs[4][32][36];
    __shared__ float Hs[32][8];

    const int tid = threadIdx.x, lane = tid & 63, wave = tid >> 6;
    const int quad = lane >> 4, l16 = lane & 15;
    const int m0 = blockIdx.x * 32;
    const int b2 = m0 / HW, rem = m0 - b2*HW;
    const int y0 = rem / W, x0 = rem - (rem/W)*W;
    const int co0 = blockIdx.y * 8;          // 32 interleaved cols = 8 co

    if (!FIRST){
        const ushort* gsrc = hprev + (size_t)b2*HP*WP*CO;
        for (int c = tid; c < TOT; c += 256){
            int pix = c / CH8, ch = c - pix*CH8;
            int prow = pix / PPX, ppx = pix - prow*PPX;
            *(uint4*)&patch[pix*PCO + ch*8] =
                *(const uint4*)(gsrc + ((size_t)(y0+prow)*WP + (x0+ppx))*CO + ch*8);
        }
        __syncthreads();

        const int tn0 = blockIdx.y*2;
        const ushort* bptr0 = Whpk + ((size_t)tn0*KCH*64 + lane)*8;
        const ushort* bptr1 = Whpk + ((size_t)(tn0+1)*KCH*64 + lane)*8;

        int labase[2];
        #pragma unroll
        for (int s = 0; s < 2; ++s){
            int p = s*16 + l16;
            int rp = p / W_T, xp = p - rp*W_T;
            labase[s] = (rp*PPX + xp)*PCO + quad*8;
        }

        f32x4 acc[2][2] = {};
        const int nj = (KCH - wave + 3) >> 2;
        #pragma unroll
        for (int j = 0; j < NJ; ++j){
            if (j < nj){
                const int it = wave + 4*j;
                const int tap = it / CPT, ci0 = (it - tap*CPT)*32;
                const int kh = tap/3, kw = tap - (tap/3)*3;
                const int off = (kh*PPX + kw)*PCO + ci0;
                s16x8 b0 = *(const s16x8*)(bptr0 + (size_t)it*512);
                s16x8 b1 = *(const s16x8*)(bptr1 + (size_t)it*512);
                s16x8 a0 = *(const s16x8*)&patch[labase[0] + off];
                s16x8 a1 = *(const s16x8*)&patch[labase[1] + off];
                acc[0][0] = __builtin_amdgcn_mfma_f32_16x16x32_bf16(a0, b0, acc[0][0], 0,0,0);
                acc[0][1] = __builtin_amdgcn_mfma_f32_16x16x32_bf16(a0, b1, acc[0][1], 0,0,0);
                acc[1][0] = __builtin_amdgcn_mfma_f32_16x16x32_bf16(a1, b0, acc[1][0], 0,0,0);
                acc[1][1] = __builtin_amdgcn_mfma_f32_16x16x32_bf16(a1, b1, acc[1][1], 0,0,0);
            }
        }
        #pragma unroll
        for (int s = 0; s < 2; ++s)
            #pragma unroll
            for (int nt = 0; nt < 2; ++nt)
                #pragma unroll
                for (int r = 0; r < 4; ++r)
                    Zs[wave][s*16 + quad*4 + r][nt*16 + l16] = acc[s][nt][r];
        __syncthreads();
    }

    // gates: 32 px x 8 co, one (pixel,co) per thread
    {
        const int px = tid >> 3, coin = tid & 7;
        const int m = m0 + px;
        const int rr = m - b2*HW;
        const int co = co0 + coin;
        const size_t zrow = (size_t)(b2*TSTEPS + t)*HW + rr;
        const float4 zx = *(const float4*)&Zx[zrow*N4 + blockIdx.y*32 + coin*4];
        float zi = zx.x, zf = zx.y, zg = zx.z, zo = zx.w;
        if (!FIRST){
            #pragma unroll
            for (int w = 0; w < 4; ++w){
                const float4 s = *(const float4*)&Zs[w][px][coin*4];
                zi += s.x; zf += s.y; zg += s.z; zo += s.w;
            }
        }
        const float iv = hsig(zi), fv = hsig(zf);
        const float gv = tanhf(zg), ov = hsig(zo);
        const float cold = FIRST ? 0.f : cst[(size_t)m*CO + co];
        const float cn = fv*cold + iv*gv;
        cst[(size_t)m*CO + co] = cn;
        const float h = ov * tanhf(cn);
        const int y = rr / W, x = rr - (rr/W)*W;
        hnew[((size_t)b2*HP*WP + (y+1)*WP + (x+1))*CO + co] = f2bf(h);
        Hs[px][coin] = (h - mmean[co])*rsqrtf(mvar[co]+1e-3f)*gamma[co] + beta[co];
    }
    __syncthreads();

    // upsampled store: 32 px x 4 positions x 8 co
    if (OUT_BF16){
        if (tid < 128){
            const int px = tid >> 2, q = tid & 3;
            const int ypos = q >> 1, xpos = q & 1;
            const int m = m0 + px;
            const int rr = m - b2*HW;
            const int y = rr / W, x = rr - (rr/W)*W;
            const float* hs = &Hs[px][0];
            uint4 v;
            v.x = pack2bf(hs[0], hs[1]); v.y = pack2bf(hs[2], hs[3]);
            v.z = pack2bf(hs[4], hs[5]); v.w = pack2bf(hs[6], hs[7]);
            ushort* o = (ushort*)outp;
            const size_t opix = ((size_t)(b2*TSTEPS + t)*(2*H+2) + 2*y+1+ypos)*(size_t)(2*W+2) + 2*x+1+xpos;
            *(uint4*)&o[opix*CO + co0] = v;
        }
    } else {
        const int px = tid >> 3, q = (tid >> 1) & 3, half = tid & 1;
        const int ypos = q >> 1, xpos = q & 1;
        const int m = m0 + px;
        const int rr = m - b2*HW;
        const int y = rr / W, x = rr - (rr/W)*W;
        float4 v = *(const float4*)&Hs[px][half*4];
        float* o = (float*)outp;
        const size_t opix = ((size_t)(b2*TSTEPS + t)*(2*H) + 2*y+ypos)*(size_t)(2*W) + 2*x+xpos;
        *(float4*)&o[opix*CO + co0 + half*4] = v;
    }
}

template<int CI, int CO, int H, int W, int OUT_BF16>
static void run_block(const ushort* apad, const ushort* Wxp, const ushort* Whp, const float* bias,
                      const float* g, const float* be, const float* mm, const float* mv,
                      float* Zx, ushort* hApad, ushort* hBpad, float* cbuf, void* out,
                      hipStream_t stream)
{
    const int M = BATCH * TSTEPS * H * W;
    dim3 gx(M / 32, (4*CO) / 128);
    convx_k<CI, CO, H, W><<<gx, 256, 0, stream>>>(apad, Wxp, bias, Zx);

    const size_t hbytes = (size_t)BATCH * (H+2) * (W+2) * CO * sizeof(ushort);
    hipMemsetAsync(hApad, 0, hbytes, stream);
    hipMemsetAsync(hBpad, 0, hbytes, stream);

    dim3 gs((BATCH * H * W) / 32, (4*CO) / 32);
    for (int t = 0; t < TSTEPS; ++t){
        const ushort* hp = (t & 1) ? hBpad : hApad;
        ushort* hn = (t & 1) ? hApad : hBpad;
        if (t == 0)
            step_k<CO, H, W, OUT_BF16, 1><<<gs, 256, 0, stream>>>(Zx, Whp, hp, hn, cbuf, g, be, mm, mv, out, t);
        else
            step_k<CO, H, W, OUT_BF16, 0><<<gs, 256, 0, stream>>>(Zx, Whp, hp, hn, cbuf, g, be, mm, mv, out, t);
    }
}

extern "C" void kernel_launch(void* const* d_in, const int* in_sizes, int n_in,
                              void* d_out, int out_size, void* d_ws, size_t ws_size,
                              hipStream_t stream) {
    const float* x   = (const float*)d_in[0];
    const float* Wx1 = (const float*)d_in[1];  const float* Wh1 = (const float*)d_in[2];
    const float* b1  = (const float*)d_in[3];  const float* g1  = (const float*)d_in[4];
    const float* be1 = (const float*)d_in[5];  const float* mm1 = (const float*)d_in[6];
    const float* mv1 = (const float*)d_in[7];
    const float* Wx2 = (const float*)d_in[8];  const float* Wh2 = (const float*)d_in[9];
    const float* b2  = (const float*)d_in[10]; const float* g2  = (const float*)d_in[11];
    const float* be2 = (const float*)d_in[12]; const float* mm2 = (const float*)d_in[13];
    const float* mv2 = (const float*)d_in[14];
    const float* Wx3 = (const float*)d_in[15]; const float* Wh3 = (const float*)d_in[16];
    const float* b3  = (const float*)d_in[17]; const float* g3  = (const float*)d_in[18];
    const float* be3 = (const float*)d_in[19]; const float* mm3 = (const float*)d_in[20];
    const float* mv3 = (const float*)d_in[21];

    char* ws = (char*)d_ws;
    size_t off = 0;
    auto alloc = [&](size_t bytes) { char* p = ws + off; off += (bytes + 255) & ~(size_t)255; return p; };

    float*  Zx    = (float*)alloc(8388608ull * 4);
    float*  cbuf  = (float*)alloc(262144ull * 4);
    ushort* xpad  = (ushort*)alloc(995328ull * 2);       // 16 x 18x18 x 192
    ushort* x2pad = (ushort*)alloc(2367488ull * 2);      // 16 x 34x34 x 128
    ushort* x3pad = (ushort*)alloc(4460544ull * 2);      // 16 x 66x66 x 64
    ushort* hApad = (ushort*)alloc(278784ull * 2);
    ushort* hBpad = (ushort*)alloc(278784ull * 2);
    ushort* Wxp1  = (ushort*)alloc(884736ull * 2);
    ushort* Wxp2  = (ushort*)alloc(294912ull * 2);
    ushort* Wxp3  = (ushort*)alloc(73728ull * 2);
    ushort* Whp1  = (ushort*)alloc(589824ull * 2);
    ushort* Whp2  = (ushort*)alloc(147456ull * 2);
    ushort* Whp3  = (ushort*)alloc(36864ull * 2);

    hipMemsetAsync(xpad,  0, 995328ull * 2, stream);
    hipMemsetAsync(x2pad, 0, 2367488ull * 2, stream);
    hipMemsetAsync(x3pad, 0, 4460544ull * 2, stream);

    prep_kernel<<<(SZ_PREP + 255) / 256, 256, 0, stream>>>(
        x, Wx1, Wh1, Wx2, Wh2, Wx3, Wh3,
        xpad, Wxp1, Whp1, Wxp2, Whp2, Wxp3, Whp3);

    run_block<192, 128, 16, 16, 1>(xpad,  Wxp1, Whp1, b1, g1, be1, mm1, mv1, Zx, hApad, hBpad, cbuf, x2pad, stream);
    run_block<128,  64, 32, 32, 1>(x2pad, Wxp2, Whp2, b2, g2, be2, mm2, mv2, Zx, hApad, hBpad, cbuf, x3pad, stream);
    run_block< 64,  32, 64, 64, 0>(x3pad, Wxp3, Whp3, b3, g3, be3, mm3, mv3, Zx, hApad, hBpad, cbuf, d_out, stream);
}

// Round 13
// 281.926 us; speedup vs baseline: 1.7231x; 1.1026x over previous
//
#include <hip/hip_runtime.h>
#include <math.h>

#define BATCH 2
#define TSTEPS 8

typedef __attribute__((ext_vector_type(8))) short s16x8;   // 8 bf16
typedef __attribute__((ext_vector_type(4))) float f32x4;   // MFMA accum

__device__ __forceinline__ float hsig(float v){ return fminf(fmaxf(0.2f*v+0.5f,0.f),1.f); }
__device__ __forceinline__ ushort f2bf(float f){
    uint u = __builtin_bit_cast(uint, f);
    u = (u + 0x7FFFu + ((u >> 16) & 1u)) >> 16;
    return (ushort)u;
}
__device__ __forceinline__ uint pack2bf(float lo, float hi){
    return (uint)f2bf(lo) | ((uint)f2bf(hi) << 16);
}

// pack W[k][g*Co+co] fp32 -> fragment-linear bf16:
// dst[((t_n*KCH + c)*64 + lane)*8 + j] = W[k=c*32+quad*8+j][n'=t_n*16+l16 = co*4+g]
template<int KCH, int Co>
__device__ __forceinline__ void packw(const float* __restrict__ W, ushort* __restrict__ dst, int d){
    int j = d & 7, lane = (d >> 3) & 63;
    int q = lane >> 4, l = lane & 15;
    int rest = d >> 9;
    int c = rest % KCH, t_n = rest / KCH;
    int k = c*32 + q*8 + j;
    int np = t_n*16 + l;
    int g = np & 3, co = np >> 2;
    dst[d] = f2bf(W[(size_t)k*(4*Co) + g*Co + co]);
}

#define SZ_X    786432
#define SZ_WX1  884736
#define SZ_WH1  589824
#define SZ_WX2  294912
#define SZ_WH2  147456
#define SZ_WX3  73728
#define SZ_WH3  36864
#define SZ_PREP (SZ_X+SZ_WX1+SZ_WH1+SZ_WX2+SZ_WH2+SZ_WX3+SZ_WH3)

__global__ void prep_kernel(const float* __restrict__ x,
    const float* __restrict__ Wx1, const float* __restrict__ Wh1,
    const float* __restrict__ Wx2, const float* __restrict__ Wh2,
    const float* __restrict__ Wx3, const float* __restrict__ Wh3,
    ushort* __restrict__ xpad,
    ushort* __restrict__ Wxp1, ushort* __restrict__ Whp1,
    ushort* __restrict__ Wxp2, ushort* __restrict__ Whp2,
    ushort* __restrict__ Wxp3, ushort* __restrict__ Whp3)
{
    int i = blockIdx.x * 256 + threadIdx.x;
    if (i < SZ_X){
        int c = i % 192; int r = i / 192;
        int xx = r % 16; r /= 16; int yy = r % 16; int bt = r / 16;
        xpad[((size_t)bt*18*18 + (yy+1)*18 + (xx+1))*192 + c] = f2bf(x[i]);
        return;
    } i -= SZ_X;
    if (i < SZ_WX1){ packw<54,128>(Wx1, Wxp1, i); return; } i -= SZ_WX1;
    if (i < SZ_WH1){ packw<36,128>(Wh1, Whp1, i); return; } i -= SZ_WH1;
    if (i < SZ_WX2){ packw<36, 64>(Wx2, Wxp2, i); return; } i -= SZ_WX2;
    if (i < SZ_WH2){ packw<18, 64>(Wh2, Whp2, i); return; } i -= SZ_WH2;
    if (i < SZ_WX3){ packw<18, 32>(Wx3, Wxp3, i); return; } i -= SZ_WX3;
    if (i < SZ_WH3){ packw< 9, 32>(Wh3, Whp3, i); }
}

// ---------------------------------------------------------------------------
// Full convx (block1 only): wg 32 px x 128 cols, wave = 32px x 32 cols.
// ---------------------------------------------------------------------------
template<int CI, int CO, int H, int W>
__global__ __launch_bounds__(256) void convx_k(
    const ushort* __restrict__ Apad, const ushort* __restrict__ Wpk,
    const float* __restrict__ bias, float* __restrict__ Zx)
{
    constexpr int W_T = (W < 32) ? W : 32;
    constexpr int ROWS = 32 / W_T;
    constexpr int PR = ROWS + 2, PPX = W_T + 2;
    constexpr int PCI = CI + 8;
    constexpr int KCH = 9*CI/32, CPT = CI/32;
    constexpr int HW = H*W, HP = H+2, WP = W+2;
    constexpr int N4 = 4*CO;
    constexpr int CH8 = CI/8;
    constexpr int TOT = PR*PPX*CH8;

    __shared__ ushort patch[PR*PPX*PCI];
    __shared__ float Zsc[32][132];

    const int tid = threadIdx.x, lane = tid & 63, wave = tid >> 6;
    const int quad = lane >> 4, l16 = lane & 15;
    const int m0 = blockIdx.x * 32;
    const int bt = m0 / HW, rem = m0 - bt*HW;
    const int y0 = rem / W, x0 = rem - (rem/W)*W;

    const ushort* gsrc = Apad + (size_t)bt*HP*WP*CI;
    for (int c = tid; c < TOT; c += 256){
        int pix = c / CH8, ch = c - pix*CH8;
        int prow = pix / PPX, ppx = pix - prow*PPX;
        *(uint4*)&patch[pix*PCI + ch*8] =
            *(const uint4*)(gsrc + ((size_t)(y0+prow)*WP + (x0+ppx))*CI + ch*8);
    }
    __syncthreads();

    const int tn0 = blockIdx.y*8 + wave*2;
    const ushort* bptr0 = Wpk + ((size_t)tn0*KCH*64 + lane)*8;
    const ushort* bptr1 = Wpk + ((size_t)(tn0+1)*KCH*64 + lane)*8;

    int labase[2];
    #pragma unroll
    for (int s = 0; s < 2; ++s){
        int p = s*16 + l16;
        int rp = p / W_T, xp = p - rp*W_T;
        labase[s] = (rp*PPX + xp)*PCI + quad*8;
    }

    f32x4 acc[2][2] = {};
    #pragma unroll
    for (int it = 0; it < KCH; ++it){
        const int tap = it / CPT, ci0 = (it - tap*CPT)*32;
        const int kh = tap/3, kw = tap - (tap/3)*3;
        const int off = (kh*PPX + kw)*PCI + ci0;
        s16x8 b0 = *(const s16x8*)(bptr0 + (size_t)it*512);
        s16x8 b1 = *(const s16x8*)(bptr1 + (size_t)it*512);
        s16x8 a0 = *(const s16x8*)&patch[labase[0] + off];
        s16x8 a1 = *(const s16x8*)&patch[labase[1] + off];
        acc[0][0] = __builtin_amdgcn_mfma_f32_16x16x32_bf16(a0, b0, acc[0][0], 0,0,0);
        acc[0][1] = __builtin_amdgcn_mfma_f32_16x16x32_bf16(a0, b1, acc[0][1], 0,0,0);
        acc[1][0] = __builtin_amdgcn_mfma_f32_16x16x32_bf16(a1, b0, acc[1][0], 0,0,0);
        acc[1][1] = __builtin_amdgcn_mfma_f32_16x16x32_bf16(a1, b1, acc[1][1], 0,0,0);
    }

    #pragma unroll
    for (int s = 0; s < 2; ++s){
        #pragma unroll
        for (int nt = 0; nt < 2; ++nt){
            const int col = blockIdx.y*128 + wave*32 + nt*16 + l16;
            const float bv = bias[(col & 3)*CO + (col >> 2)];
            #pragma unroll
            for (int r = 0; r < 4; ++r)
                Zsc[s*16 + quad*4 + r][wave*32 + nt*16 + l16] = acc[s][nt][r] + bv;
        }
    }
    __syncthreads();

    #pragma unroll
    for (int i = 0; i < 4; ++i){
        int c = i*256 + tid;
        int row = c >> 5, cc = (c & 31) << 2;
        *(float4*)&Zx[(size_t)(m0+row)*N4 + blockIdx.y*128 + cc] = *(float4*)&Zsc[row][cc];
    }
}

// ---------------------------------------------------------------------------
// Device role: conv-x for ONE time slice t (same body as convx_k, slice-based).
// ---------------------------------------------------------------------------
template<int CI, int CO, int H, int W>
__device__ __forceinline__ void conv_slice_role(char* smem, int lbid, int t,
    const ushort* __restrict__ Apad, const ushort* __restrict__ Wpk,
    const float* __restrict__ bias, float* __restrict__ Zx)
{
    constexpr int W_T = (W < 32) ? W : 32;
    constexpr int PR = (32/W_T) + 2, PPX = W_T + 2;
    constexpr int PCI = CI + 8;
    constexpr int KCH = 9*CI/32, CPT = CI/32;
    constexpr int HW = H*W, HP = H+2, WP = W+2;
    constexpr int N4 = 4*CO;
    constexpr int CH8 = CI/8;
    constexpr int TOT = PR*PPX*CH8;
    constexpr int TPB = HW/32;
    constexpr int PXT = 2*TPB;

    ushort* patch = (ushort*)smem;
    float* Zsc = (float*)(smem + PR*PPX*PCI*2);   // [32][132]

    const int tid = threadIdx.x, lane = tid & 63, wave = tid >> 6;
    const int quad = lane >> 4, l16 = lane & 15;
    const int lx = lbid % PXT, ly = lbid / PXT;
    const int b = lx / TPB;
    const int idx0 = (lx - b*TPB)*32;
    const int bt = b*TSTEPS + t;
    const int m0 = bt*HW + idx0;
    const int y0 = idx0 / W, x0 = idx0 - (idx0/W)*W;

    const ushort* gsrc = Apad + (size_t)bt*HP*WP*CI;
    for (int c = tid; c < TOT; c += 256){
        int pix = c / CH8, ch = c - pix*CH8;
        int prow = pix / PPX, ppx = pix - prow*PPX;
        *(uint4*)&patch[pix*PCI + ch*8] =
            *(const uint4*)(gsrc + ((size_t)(y0+prow)*WP + (x0+ppx))*CI + ch*8);
    }
    __syncthreads();

    const int tn0 = ly*8 + wave*2;
    const ushort* bptr0 = Wpk + ((size_t)tn0*KCH*64 + lane)*8;
    const ushort* bptr1 = Wpk + ((size_t)(tn0+1)*KCH*64 + lane)*8;

    int labase[2];
    #pragma unroll
    for (int s = 0; s < 2; ++s){
        int p = s*16 + l16;
        int rp = p / W_T, xp = p - rp*W_T;
        labase[s] = (rp*PPX + xp)*PCI + quad*8;
    }

    f32x4 acc[2][2] = {};
    #pragma unroll
    for (int it = 0; it < KCH; ++it){
        const int tap = it / CPT, ci0 = (it - tap*CPT)*32;
        const int kh = tap/3, kw = tap - (tap/3)*3;
        const int off = (kh*PPX + kw)*PCI + ci0;
        s16x8 b0 = *(const s16x8*)(bptr0 + (size_t)it*512);
        s16x8 b1 = *(const s16x8*)(bptr1 + (size_t)it*512);
        s16x8 a0 = *(const s16x8*)&patch[labase[0] + off];
        s16x8 a1 = *(const s16x8*)&patch[labase[1] + off];
        acc[0][0] = __builtin_amdgcn_mfma_f32_16x16x32_bf16(a0, b0, acc[0][0], 0,0,0);
        acc[0][1] = __builtin_amdgcn_mfma_f32_16x16x32_bf16(a0, b1, acc[0][1], 0,0,0);
        acc[1][0] = __builtin_amdgcn_mfma_f32_16x16x32_bf16(a1, b0, acc[1][0], 0,0,0);
        acc[1][1] = __builtin_amdgcn_mfma_f32_16x16x32_bf16(a1, b1, acc[1][1], 0,0,0);
    }

    #pragma unroll
    for (int s = 0; s < 2; ++s){
        #pragma unroll
        for (int nt = 0; nt < 2; ++nt){
            const int col = ly*128 + wave*32 + nt*16 + l16;
            const float bv = bias[(col & 3)*CO + (col >> 2)];
            #pragma unroll
            for (int r = 0; r < 4; ++r)
                Zsc[(s*16 + quad*4 + r)*132 + wave*32 + nt*16 + l16] = acc[s][nt][r] + bv;
        }
    }
    __syncthreads();

    #pragma unroll
    for (int i = 0; i < 4; ++i){
        int c = i*256 + tid;
        int row = c >> 5, cc = (c & 31) << 2;
        *(float4*)&Zx[(size_t)(m0+row)*N4 + ly*128 + cc] = *(float4*)&Zsc[row*132 + cc];
    }
}

// ---------------------------------------------------------------------------
// Device role: one LSTM step (32 px x 32 interleaved cols per wg, split-K over
// 4 waves, LDS reduce, fused gates+BN+2x2 upsample). Runtime FIRST.
// ---------------------------------------------------------------------------
template<int CO, int H, int W, int OUT_BF16>
__device__ __forceinline__ void step_role(char* smem, int lbid, int t, int first,
    const float* __restrict__ Zx, const ushort* __restrict__ Whpk,
    const ushort* __restrict__ hprev, ushort* __restrict__ hnew,
    float* __restrict__ cst,
    const float* __restrict__ gamma, const float* __restrict__ beta,
    const float* __restrict__ mmean, const float* __restrict__ mvar,
    void* __restrict__ outp)
{
    constexpr int W_T = (W < 32) ? W : 32;
    constexpr int PR = (32/W_T) + 2, PPX = W_T + 2;
    constexpr int PCO = CO + 8;
    constexpr int KCH = 9*CO/32, CPT = CO/32;
    constexpr int NJ = (KCH + 3)/4;
    constexpr int HW = H*W, HP = H+2, WP = W+2;
    constexpr int N4 = 4*CO;
    constexpr int CH8 = CO/8;
    constexpr int TOT = PR*PPX*CH8;
    constexpr int PT = (BATCH*HW)/32;

    ushort* patch = (ushort*)smem;
    float* Zs = (float*)(smem + PR*PPX*PCO*2);              // [4][32][36]
    float* Hs = (float*)(smem + PR*PPX*PCO*2 + 18432);      // [32][8]

    const int tid = threadIdx.x, lane = tid & 63, wave = tid >> 6;
    const int quad = lane >> 4, l16 = lane & 15;
    const int pxt = lbid % PT, colIdx = lbid / PT;
    const int m0 = pxt * 32;
    const int b2 = m0 / HW, rem = m0 - b2*HW;
    const int y0 = rem / W, x0 = rem - (rem/W)*W;
    const int co0 = colIdx * 8;

    if (!first){
        const ushort* gsrc = hprev + (size_t)b2*HP*WP*CO;
        for (int c = tid; c < TOT; c += 256){
            int pix = c / CH8, ch = c - pix*CH8;
            int prow = pix / PPX, ppx = pix - prow*PPX;
            *(uint4*)&patch[pix*PCO + ch*8] =
                *(const uint4*)(gsrc + ((size_t)(y0+prow)*WP + (x0+ppx))*CO + ch*8);
        }
        __syncthreads();

        const int tn0 = colIdx*2;
        const ushort* bptr0 = Whpk + ((size_t)tn0*KCH*64 + lane)*8;
        const ushort* bptr1 = Whpk + ((size_t)(tn0+1)*KCH*64 + lane)*8;

        int labase[2];
        #pragma unroll
        for (int s = 0; s < 2; ++s){
            int p = s*16 + l16;
            int rp = p / W_T, xp = p - rp*W_T;
            labase[s] = (rp*PPX + xp)*PCO + quad*8;
        }

        f32x4 acc[2][2] = {};
        const int nj = (KCH - wave + 3) >> 2;
        #pragma unroll
        for (int j = 0; j < NJ; ++j){
            if (j < nj){
                const int it = wave + 4*j;
                const int tap = it / CPT, ci0 = (it - tap*CPT)*32;
                const int kh = tap/3, kw = tap - (tap/3)*3;
                const int off = (kh*PPX + kw)*PCO + ci0;
                s16x8 b0 = *(const s16x8*)(bptr0 + (size_t)it*512);
                s16x8 b1 = *(const s16x8*)(bptr1 + (size_t)it*512);
                s16x8 a0 = *(const s16x8*)&patch[labase[0] + off];
                s16x8 a1 = *(const s16x8*)&patch[labase[1] + off];
                acc[0][0] = __builtin_amdgcn_mfma_f32_16x16x32_bf16(a0, b0, acc[0][0], 0,0,0);
                acc[0][1] = __builtin_amdgcn_mfma_f32_16x16x32_bf16(a0, b1, acc[0][1], 0,0,0);
                acc[1][0] = __builtin_amdgcn_mfma_f32_16x16x32_bf16(a1, b0, acc[1][0], 0,0,0);
                acc[1][1] = __builtin_amdgcn_mfma_f32_16x16x32_bf16(a1, b1, acc[1][1], 0,0,0);
            }
        }
        #pragma unroll
        for (int s = 0; s < 2; ++s)
            #pragma unroll
            for (int nt = 0; nt < 2; ++nt)
                #pragma unroll
                for (int r = 0; r < 4; ++r)
                    Zs[(wave*32 + s*16 + quad*4 + r)*36 + nt*16 + l16] = acc[s][nt][r];
        __syncthreads();
    }

    // gates: 32 px x 8 co
    {
        const int px = tid >> 3, coin = tid & 7;
        const int m = m0 + px;
        const int rr = m - b2*HW;
        const int co = co0 + coin;
        const size_t zrow = (size_t)(b2*TSTEPS + t)*HW + rr;
        const float4 zx = *(const float4*)&Zx[zrow*N4 + colIdx*32 + coin*4];
        float zi = zx.x, zf = zx.y, zg = zx.z, zo = zx.w;
        if (!first){
            #pragma unroll
            for (int w = 0; w < 4; ++w){
                const float4 s = *(const float4*)&Zs[(w*32 + px)*36 + coin*4];
                zi += s.x; zf += s.y; zg += s.z; zo += s.w;
            }
        }
        const float iv = hsig(zi), fv = hsig(zf);
        const float gv = tanhf(zg), ov = hsig(zo);
        const float cold = first ? 0.f : cst[(size_t)m*CO + co];
        const float cn = fv*cold + iv*gv;
        cst[(size_t)m*CO + co] = cn;
        const float h = ov * tanhf(cn);
        const int y = rr / W, x = rr - (rr/W)*W;
        hnew[((size_t)b2*HP*WP + (y+1)*WP + (x+1))*CO + co] = f2bf(h);
        Hs[px*8 + coin] = (h - mmean[co])*rsqrtf(mvar[co]+1e-3f)*gamma[co] + beta[co];
    }
    __syncthreads();

    if (OUT_BF16){
        if (tid < 128){
            const int px = tid >> 2, q = tid & 3;
            const int ypos = q >> 1, xpos = q & 1;
            const int m = m0 + px;
            const int rr = m - b2*HW;
            const int y = rr / W, x = rr - (rr/W)*W;
            const float* hs = &Hs[px*8];
            uint4 v;
            v.x = pack2bf(hs[0], hs[1]); v.y = pack2bf(hs[2], hs[3]);
            v.z = pack2bf(hs[4], hs[5]); v.w = pack2bf(hs[6], hs[7]);
            ushort* o = (ushort*)outp;
            const size_t opix = ((size_t)(b2*TSTEPS + t)*(2*H+2) + 2*y+1+ypos)*(size_t)(2*W+2) + 2*x+1+xpos;
            *(uint4*)&o[opix*CO + co0] = v;
        }
    } else {
        const int px = tid >> 3, q = (tid >> 1) & 3, half = tid & 1;
        const int ypos = q >> 1, xpos = q & 1;
        const int m = m0 + px;
        const int rr = m - b2*HW;
        const int y = rr / W, x = rr - (rr/W)*W;
        float4 v = *(const float4*)&Hs[px*8 + half*4];
        float* o = (float*)outp;
        const size_t opix = ((size_t)(b2*TSTEPS + t)*(2*H) + 2*y+ypos)*(size_t)(2*W) + 2*x+xpos;
        *(float4*)&o[opix*CO + co0 + half*4] = v;
    }
}

// ---------------------------------------------------------------------------
// Mega pipeline kernel: up to 5 independent roles per launch.
// LDS = max over roles (C2: 27744 patch + 16896 Zsc = 44640 B).
// ---------------------------------------------------------------------------
__global__ __launch_bounds__(256) void mega(
    int e1, int e2, int e3, int e4,
    int t1, int t2, int t3, int t4, int t5,
    int f1, int f2, int f3,
    const float* Zx1, const ushort* Whp1, const ushort* h1p, ushort* h1n, float* c1,
    const float* g1, const float* be1, const float* mm1, const float* mv1, ushort* x2pad,
    const ushort* Wxp2, const float* b2v, float* Zx2,
    const ushort* Whp2, const ushort* h2p, ushort* h2n, float* c2,
    const float* g2, const float* be2, const float* mm2, const float* mv2, ushort* x3pad,
    const ushort* Wxp3, const float* b3v, float* Zx3,
    const ushort* Whp3, const ushort* h3p, ushort* h3n, float* c3,
    const float* g3, const float* be3, const float* mm3, const float* mv3, float* outp)
{
    __shared__ __align__(16) char smem[44672];
    const int bid = blockIdx.x;
    if (bid < e1){
        step_role<128,16,16,1>(smem, bid, t1, f1, Zx1, Whp1, h1p, h1n, c1, g1, be1, mm1, mv1, x2pad);
        return;
    }
    if (bid < e2){
        conv_slice_role<128,64,32,32>(smem, bid - e1, t2, x2pad, Wxp2, b2v, Zx2);
        return;
    }
    if (bid < e3){
        step_role<64,32,32,1>(smem, bid - e2, t3, f2, Zx2, Whp2, h2p, h2n, c2, g2, be2, mm2, mv2, x3pad);
        return;
    }
    if (bid < e4){
        conv_slice_role<64,32,64,64>(smem, bid - e3, t4, x3pad, Wxp3, b3v, Zx3);
        return;
    }
    step_role<32,64,64,0>(smem, bid - e4, t5, f3, Zx3, Whp3, h3p, h3n, c3, g3, be3, mm3, mv3, outp);
}

extern "C" void kernel_launch(void* const* d_in, const int* in_sizes, int n_in,
                              void* d_out, int out_size, void* d_ws, size_t ws_size,
                              hipStream_t stream) {
    const float* x   = (const float*)d_in[0];
    const float* Wx1 = (const float*)d_in[1];  const float* Wh1 = (const float*)d_in[2];
    const float* b1  = (const float*)d_in[3];  const float* g1  = (const float*)d_in[4];
    const float* be1 = (const float*)d_in[5];  const float* mm1 = (const float*)d_in[6];
    const float* mv1 = (const float*)d_in[7];
    const float* Wx2 = (const float*)d_in[8];  const float* Wh2 = (const float*)d_in[9];
    const float* b2  = (const float*)d_in[10]; const float* g2  = (const float*)d_in[11];
    const float* be2 = (const float*)d_in[12]; const float* mm2 = (const float*)d_in[13];
    const float* mv2 = (const float*)d_in[14];
    const float* Wx3 = (const float*)d_in[15]; const float* Wh3 = (const float*)d_in[16];
    const float* b3  = (const float*)d_in[17]; const float* g3  = (const float*)d_in[18];
    const float* be3 = (const float*)d_in[19]; const float* mm3 = (const float*)d_in[20];
    const float* mv3 = (const float*)d_in[21];

    char* ws = (char*)d_ws;
    size_t off = 0;
    auto alloc = [&](size_t bytes) { char* p = ws + off; off += (bytes + 255) & ~(size_t)255; return p; };

    float*  Zx1 = (float*)alloc(2097152ull * 4);   //  4096 x 512
    float*  Zx2 = (float*)alloc(4194304ull * 4);   // 16384 x 256
    float*  Zx3 = (float*)alloc(8388608ull * 4);   // 65536 x 128
    float*  c1  = (float*)alloc(65536ull * 4);
    float*  c2  = (float*)alloc(131072ull * 4);
    float*  c3  = (float*)alloc(262144ull * 4);

    // contiguous zero region (one memset): pads + h halo buffers
    char* zbase = alloc(17685504ull);
    ushort* xpad  = (ushort*)zbase;                    //  995,328 u (16x18x18x192)
    ushort* x2pad = xpad  + 995328;                    // 2,367,488 u (16x34x34x128)
    ushort* x3pad = x2pad + 2367488;                   // 4,460,544 u (16x66x66x64)
    ushort* h1A   = x3pad + 4460544;                   //    82,944 u (2x18x18x128)
    ushort* h1B   = h1A + 82944;
    ushort* h2A   = h1B + 82944;                       //   147,968 u (2x34x34x64)
    ushort* h2B   = h2A + 147968;
    ushort* h3A   = h2B + 147968;                      //   278,784 u (2x66x66x32)
    ushort* h3B   = h3A + 278784;

    ushort* Wxp1 = (ushort*)alloc(884736ull * 2);
    ushort* Wxp2 = (ushort*)alloc(294912ull * 2);
    ushort* Wxp3 = (ushort*)alloc(73728ull * 2);
    ushort* Whp1 = (ushort*)alloc(589824ull * 2);
    ushort* Whp2 = (ushort*)alloc(147456ull * 2);
    ushort* Whp3 = (ushort*)alloc(36864ull * 2);

    hipMemsetAsync(zbase, 0, 17685504ull, stream);

    prep_kernel<<<(SZ_PREP + 255) / 256, 256, 0, stream>>>(
        x, Wx1, Wh1, Wx2, Wh2, Wx3, Wh3,
        xpad, Wxp1, Whp1, Wxp2, Whp2, Wxp3, Whp3);

    // block1 conv-x over all t (M = 4096)
    convx_k<192, 128, 16, 16><<<dim3(128, 4), 256, 0, stream>>>(xpad, Wxp1, b1, Zx1);

    // temporal pipeline: L(j) = { S1(j), C2(j-1), S2(j-2), C3(j-3), S3(j-4) }
    for (int j = 0; j < 12; ++j){
        const int a1 = (j < 8),            t1 = a1 ? j     : 0;
        const int a2 = (j >= 1 && j <= 8), tc2 = a2 ? j - 1 : 0;
        const int a3 = (j >= 2 && j <= 9), ts2 = a3 ? j - 2 : 0;
        const int a4 = (j >= 3 && j <= 10), tc3 = a4 ? j - 3 : 0;
        const int a5 = (j >= 4),           ts3 = a5 ? j - 4 : 0;

        const int e1 = a1 ? 256 : 0;
        const int e2 = e1 + (a2 ? 128 : 0);
        const int e3 = e2 + (a3 ? 512 : 0);
        const int e4 = e3 + (a4 ? 256 : 0);
        const int e5 = e4 + (a5 ? 1024 : 0);
        if (e5 == 0) continue;

        const ushort* h1p = (t1 & 1) ? h1B : h1A;  ushort* h1n = (t1 & 1) ? h1A : h1B;
        const ushort* h2p = (ts2 & 1) ? h2B : h2A; ushort* h2n = (ts2 & 1) ? h2A : h2B;
        const ushort* h3p = (ts3 & 1) ? h3B : h3A; ushort* h3n = (ts3 & 1) ? h3A : h3B;

        mega<<<dim3(e5), 256, 0, stream>>>(
            e1, e2, e3, e4,
            t1, tc2, ts2, tc3, ts3,
            (t1 == 0), (ts2 == 0), (ts3 == 0),
            Zx1, Whp1, h1p, h1n, c1, g1, be1, mm1, mv1, x2pad,
            Wxp2, b2, Zx2,
            Whp2, h2p, h2n, c2, g2, be2, mm2, mv2, x3pad,
            Wxp3, b3, Zx3,
            Whp3, h3p, h3n, c3, g3, be3, mm3, mv3, (float*)d_out);
    }
}